// Round 4
// baseline (2159.795 us; speedup 1.0000x reference)
//
#include <hip/hip_runtime.h>
#include <cstddef>

#define TT 2048   // time steps
#define BB 256    // batch
#define DD 32     // input dim
#define HH 64     // hidden
#define GG 256    // 4*H

__device__ __forceinline__ float sigmf(float v) { return 1.0f / (1.0f + __expf(-v)); }
__device__ __forceinline__ float tanh_f(float v) { return 2.0f / (1.0f + __expf(-2.0f * v)) - 1.0f; }

// Pin 4 values into arch VGPRs at this program point. Used INSIDE the time
// loop: forces the weight arrays to be arch-VGPR-resident across iterations,
// preventing the allocator from parking them in AGPRs (which costs one
// v_accvgpr_read per FMA -- the R2/R3 VALU bloat: VGPR_Count=80 while ~100+
// values were live).
#define PIN4(a,b,c,d) asm volatile("" : "+v"(a), "+v"(b), "+v"(c), "+v"(d))

// One block per batch row; 512 threads = 8 waves.
// Waves 0-3: layer-1 recurrence engine, one step AHEAD.
// Waves 4-7: layer-2 recurrence + output projection, one step behind.
// Thread map within each group: gate g = lane>>4, unit u = 16*wave + (lane&15).
// All 4 gates of a unit are in ONE wave -> state update via 3 shfl_xor, no barrier.
// h1/h2/partials cross via double-buffered LDS; ONE barrier per step.
__global__ __launch_bounds__(512, 2)
void dlstm_kernel(const float* __restrict__ x,
                  const float* __restrict__ W1, const float* __restrict__ U1,
                  const float* __restrict__ b1,
                  const float* __restrict__ W2, const float* __restrict__ U2,
                  const float* __restrict__ b2,
                  const float* __restrict__ Wd, const float* __restrict__ bd,
                  float* __restrict__ out)
{
    const int tid = threadIdx.x;
    const int b   = blockIdx.x;
    const int wid = tid >> 6;       // 0..7
    const int l   = tid & 63;
    const int g   = l >> 4;         // gate 0..3 (i,f,c~,o in Keras order)
    const int uo  = l & 15;

    __shared__ __align__(16) float h1b[2][HH];
    __shared__ __align__(16) float h2b[2][HH];
    __shared__ float pbuf[2][4];

    if (tid < HH) { h1b[0][tid] = 0.f; h1b[1][tid] = 0.f; h2b[0][tid] = 0.f; h2b[1][tid] = 0.f; }
    if (tid < 8) pbuf[tid >> 2][tid & 3] = 0.f;
    __syncthreads();

    if (wid < 4) {
        // ================= layer-1 engine (computes h1(n) at iter n) =================
        const int u   = (wid << 4) + uo;     // 0..63
        const int col = (g << 6) + u;        // column in [0,256), gate-major
        float w1c[DD], u1c[HH];
        #pragma unroll
        for (int d = 0; d < DD; ++d) w1c[d] = W1[d * GG + col];
        #pragma unroll
        for (int j = 0; j < HH; ++j) u1c[j] = U1[j * GG + col];
        const float b1k = b1[col];
        const float bd0 = bd[0];
        float c1 = 0.f;

        const float* xrow = x + (size_t)b * (TT * DD);
        float4 xv[8];
        #pragma unroll
        for (int q = 0; q < 8; ++q) xv[q] = ((const float4*)xrow)[q];

        #pragma unroll 2
        for (int n = 0; n < TT + 2; ++n) {
            const int p = n & 1;
            if (n < TT) {
                // hard-pin the weights into arch VGPRs for this iteration
                #pragma unroll
                for (int d = 0; d < DD; d += 4) PIN4(w1c[d], w1c[d+1], w1c[d+2], w1c[d+3]);
                #pragma unroll
                for (int j = 0; j < HH; j += 4) PIN4(u1c[j], u1c[j+1], u1c[j+2], u1c[j+3]);

                // prefetch x_{n+1} (in flight under the whole step)
                const float4* xnp = (const float4*)(xrow + (size_t)((n + 1 < TT) ? n + 1 : n) * DD);
                float4 xn[8];
                #pragma unroll
                for (int q = 0; q < 8; ++q) xn[q] = xnp[q];

                float a0 = b1k, a1 = 0.f, a2 = 0.f, a3 = 0.f;
                #pragma unroll
                for (int q = 0; q < 8; ++q) {
                    a0 += xv[q].x * w1c[4*q+0];
                    a1 += xv[q].y * w1c[4*q+1];
                    a2 += xv[q].z * w1c[4*q+2];
                    a3 += xv[q].w * w1c[4*q+3];
                }
                const float4* hp = (const float4*)h1b[p];   // h1(n-1), broadcast reads
                #pragma unroll
                for (int q = 0; q < 16; ++q) {
                    float4 hv = hp[q];
                    a0 += hv.x * u1c[4*q+0];
                    a1 += hv.y * u1c[4*q+1];
                    a2 += hv.z * u1c[4*q+2];
                    a3 += hv.w * u1c[4*q+3];
                }
                float z = (a0 + a1) + (a2 + a3);
                float a = (g == 2) ? tanh_f(z) : sigmf(z);
                // intra-wave all-gather of the 4 gates of this unit
                float p16 = __shfl_xor(a, 16, 64);
                float p32 = __shfl_xor(a, 32, 64);
                float p48 = __shfl_xor(p16, 32, 64);
                float gi = (g==0) ? a   : (g==1) ? p16 : (g==2) ? p32 : p48;
                float gf = (g==0) ? p16 : (g==1) ? a   : (g==2) ? p48 : p32;
                float gc = (g==0) ? p32 : (g==1) ? p48 : (g==2) ? a   : p16;
                float go = (g==0) ? p48 : (g==1) ? p32 : (g==2) ? p16 : a;
                c1 = gf * c1 + gi * gc;
                float h = go * tanh_f(c1);
                if (g == 0) h1b[p ^ 1][u] = h;

                #pragma unroll
                for (int q = 0; q < 8; ++q) xv[q] = xn[q];
            }
            // output store: out(n-2) from partials written by B at iter n-1
            if (tid == 0 && n >= 2) {
                float s = pbuf[p][0] + pbuf[p][1] + pbuf[p][2] + pbuf[p][3];
                out[(size_t)b * TT + (n - 2)] = sigmf(s + bd0);
            }
            __syncthreads();
        }
    } else {
        // ================= layer-2 engine (computes h2(n-1) at iter n) =================
        const int w2i = wid - 4;
        const int u   = (w2i << 4) + uo;
        const int col = (g << 6) + u;
        float w2c[HH], u2c[HH];
        #pragma unroll
        for (int j = 0; j < HH; ++j) w2c[j] = W2[j * GG + col];
        #pragma unroll
        for (int j = 0; j < HH; ++j) u2c[j] = U2[j * GG + col];
        const float b2k = b2[col];
        const float wdk = Wd[u];
        float c2 = 0.f;

        #pragma unroll 2
        for (int n = 0; n < TT + 2; ++n) {
            const int p = n & 1;
            if (n >= 1 && n <= TT) {
                // hard-pin the weights into arch VGPRs for this iteration
                #pragma unroll
                for (int j = 0; j < HH; j += 4) PIN4(w2c[j], w2c[j+1], w2c[j+2], w2c[j+3]);
                #pragma unroll
                for (int j = 0; j < HH; j += 4) PIN4(u2c[j], u2c[j+1], u2c[j+2], u2c[j+3]);

                float d0 = b2k, d1 = 0.f, d2 = 0.f, d3 = 0.f;
                const float4* h1p = (const float4*)h1b[p];  // h1(n-1)
                const float4* h2p = (const float4*)h2b[p];  // h2(n-2)
                #pragma unroll
                for (int q = 0; q < 16; ++q) {
                    float4 hv = h1p[q];
                    d0 += hv.x * w2c[4*q+0];
                    d1 += hv.y * w2c[4*q+1];
                    d2 += hv.z * w2c[4*q+2];
                    d3 += hv.w * w2c[4*q+3];
                }
                #pragma unroll
                for (int q = 0; q < 16; ++q) {
                    float4 hv = h2p[q];
                    d0 += hv.x * u2c[4*q+0];
                    d1 += hv.y * u2c[4*q+1];
                    d2 += hv.z * u2c[4*q+2];
                    d3 += hv.w * u2c[4*q+3];
                }
                float z = (d0 + d1) + (d2 + d3);
                float a = (g == 2) ? tanh_f(z) : sigmf(z);
                float p16 = __shfl_xor(a, 16, 64);
                float p32 = __shfl_xor(a, 32, 64);
                float p48 = __shfl_xor(p16, 32, 64);
                float gi = (g==0) ? a   : (g==1) ? p16 : (g==2) ? p32 : p48;
                float gf = (g==0) ? p16 : (g==1) ? a   : (g==2) ? p48 : p32;
                float gc = (g==0) ? p32 : (g==1) ? p48 : (g==2) ? a   : p16;
                float go = (g==0) ? p48 : (g==1) ? p32 : (g==2) ? p16 : a;
                c2 = gf * c2 + gi * gc;
                float h = go * tanh_f(c2);
                if (g == 0) h2b[p ^ 1][u] = h;
                // projection partial for out(n-1): sum over this wave's 16 units
                float v = (g == 0) ? h * wdk : 0.f;
                v += __shfl_xor(v, 1, 64);
                v += __shfl_xor(v, 2, 64);
                v += __shfl_xor(v, 4, 64);
                v += __shfl_xor(v, 8, 64);
                if (l == 0) pbuf[p ^ 1][w2i] = v;
            }
            __syncthreads();
        }
    }
}

extern "C" void kernel_launch(void* const* d_in, const int* in_sizes, int n_in,
                              void* d_out, int out_size, void* d_ws, size_t ws_size,
                              hipStream_t stream) {
    const float* x  = (const float*)d_in[0];
    const float* W1 = (const float*)d_in[1];
    const float* U1 = (const float*)d_in[2];
    const float* b1 = (const float*)d_in[3];
    const float* W2 = (const float*)d_in[4];
    const float* U2 = (const float*)d_in[5];
    const float* b2 = (const float*)d_in[6];
    const float* Wd = (const float*)d_in[7];
    const float* bd = (const float*)d_in[8];
    float* out = (float*)d_out;

    dlstm_kernel<<<dim3(BB), dim3(512), 0, stream>>>(
        x, W1, U1, b1, W2, U2, b2, Wd, bd, out);
}

// Round 5
// 2047.148 us; speedup vs baseline: 1.0550x; 1.0550x over previous
//
#include <hip/hip_runtime.h>
#include <hip/hip_bf16.h>
#include <cstddef>

#define TT 2048   // time steps
#define BB 256    // batch
#define DD 32     // input dim
#define HH 64     // hidden
#define GG 256    // 4*H

__device__ __forceinline__ float sigmf(float v) { return 1.0f / (1.0f + __expf(-v)); }
__device__ __forceinline__ float tanh_f(float v) { return 2.0f / (1.0f + __expf(-2.0f * v)) - 1.0f; }

// ---------------- pre-kernel: zx[b][t][u*4+g] = x[b,t,:] @ W1[:, g*64+u] + b1 ----------------
// Time-parallel part of layer 1 hoisted out of the recurrence (reference does the same).
template <typename ZXT>
__global__ __launch_bounds__(256)
void zx_pre(const float* __restrict__ x, const float* __restrict__ W1,
            const float* __restrict__ b1, ZXT* __restrict__ zx)
{
    const int tb = blockIdx.x;      // t-tile of 8
    const int bb = blockIdx.y;      // batch row
    const int tid = threadIdx.x;    // 0..255 = output column c = u*4+g
    __shared__ float xs[8][DD];

    const float* xb = x + ((size_t)bb * TT + (size_t)tb * 8) * DD;
    xs[tid >> 5][tid & 31] = xb[tid];          // 8 rows x 32 = 256 floats, coalesced
    __syncthreads();

    const int u = tid >> 2, g = tid & 3;
    const int colW = g * HH + u;               // W1 column (gate-major, Keras order)
    float wcol[DD];
    #pragma unroll
    for (int d = 0; d < DD; ++d) wcol[d] = W1[d * GG + colW];
    const float bias = b1[colW];

    ZXT* zb = zx + ((size_t)bb * TT + (size_t)tb * 8) * GG;
    #pragma unroll
    for (int r = 0; r < 8; ++r) {
        float z0 = bias, z1 = 0.f, z2 = 0.f, z3 = 0.f;
        #pragma unroll
        for (int d = 0; d < DD; d += 4) {
            z0 += xs[r][d+0] * wcol[d+0];
            z1 += xs[r][d+1] * wcol[d+1];
            z2 += xs[r][d+2] * wcol[d+2];
            z3 += xs[r][d+3] * wcol[d+3];
        }
        zb[r * GG + tid] = (ZXT)((z0 + z1) + (z2 + z3));
    }
}

// ---------------- recurrence kernel ----------------
// One block per batch row; 512 threads = 8 waves. Waves 0-3: layer-1 (one step
// ahead); waves 4-7: layer-2 + projection. Thread map: unit u = wid*16+(lane&15),
// K-quarter kq = lane>>4. Each thread owns ALL 4 GATES of its unit for its
// K-chunk: every LDS h-read feeds 4 columns (4x less LDS-broadcast traffic than
// R4, which was LDS-return-bus bound at 192 ds_read_b128/step). Partial combine
// across kq + gate all-gather = 6 shfl_xor. One barrier per step.
template <typename ZXT>
__global__ __launch_bounds__(512, 2)
void dlstm_rec(const ZXT* __restrict__ zx,
               const float* __restrict__ U1,
               const float* __restrict__ W2, const float* __restrict__ U2,
               const float* __restrict__ b2,
               const float* __restrict__ Wd, const float* __restrict__ bd,
               float* __restrict__ out)
{
    const int tid = threadIdx.x;
    const int b   = blockIdx.x;
    const int wid = tid >> 6;
    const int l   = tid & 63;
    const int kq  = l >> 4;          // K-quarter AND (after combine) gate index
    const int ul  = l & 15;

    __shared__ __align__(16) float h1b[2][HH];
    __shared__ __align__(16) float h2b[2][HH + 8];   // pad: different bank phase vs h1b
    __shared__ float pbuf[2][4];

    if (tid < HH) { h1b[0][tid] = 0.f; h1b[1][tid] = 0.f; h2b[0][tid] = 0.f; h2b[1][tid] = 0.f; }
    if (tid < 8) pbuf[tid >> 2][tid & 3] = 0.f;
    __syncthreads();

    if (wid < 4) {
        // ---------- layer-1 engine: computes h1(n) at iter n ----------
        const int u = wid * 16 + ul;
        float uw[4][16];                       // U1 rows [16kq,16kq+16) x 4 gate-cols of u
        #pragma unroll
        for (int g = 0; g < 4; ++g)
            #pragma unroll
            for (int j = 0; j < 16; ++j)
                uw[g][j] = U1[(kq * 16 + j) * GG + (g * HH + u)];
        const float bd0 = bd[0];
        float c1 = 0.f;

        const ZXT* zrow = zx + (size_t)b * TT * GG;
        float zcur = (float)zrow[(size_t)0 * GG + u * 4 + kq];   // prefetched zx for t=0, own gate

        for (int n = 0; n < TT + 2; ++n) {
            const int p = n & 1;
            if (n < TT) {
                const int tn = (n + 1 < TT) ? n + 1 : n;
                float znx = (float)zrow[(size_t)tn * GG + u * 4 + kq];  // prefetch t+1

                float a0 = 0.f, a1 = 0.f, a2 = 0.f, a3 = 0.f;   // gate partials over my K-chunk
                const float4* hp = (const float4*)&h1b[p][kq * 16];
                #pragma unroll
                for (int j4 = 0; j4 < 4; ++j4) {
                    float4 hv = hp[j4];
                    a0 += hv.x * uw[0][4*j4+0]; a0 += hv.y * uw[0][4*j4+1];
                    a0 += hv.z * uw[0][4*j4+2]; a0 += hv.w * uw[0][4*j4+3];
                    a1 += hv.x * uw[1][4*j4+0]; a1 += hv.y * uw[1][4*j4+1];
                    a1 += hv.z * uw[1][4*j4+2]; a1 += hv.w * uw[1][4*j4+3];
                    a2 += hv.x * uw[2][4*j4+0]; a2 += hv.y * uw[2][4*j4+1];
                    a2 += hv.z * uw[2][4*j4+2]; a2 += hv.w * uw[2][4*j4+3];
                    a3 += hv.x * uw[3][4*j4+0]; a3 += hv.y * uw[3][4*j4+1];
                    a3 += hv.z * uw[3][4*j4+2]; a3 += hv.w * uw[3][4*j4+3];
                }
                // combine across kq lanes: round 1 (xor16) exchanges the gate-parity
                // the partner needs; round 2 (xor32) finishes. Lane ends with z of gate kq.
                float t1 = (kq & 1) ? a0 : a1;
                float t2 = (kq & 1) ? a2 : a3;
                float r1 = __shfl_xor(t1, 16, 64);
                float r2 = __shfl_xor(t2, 16, 64);
                float m1 = (kq & 1) ? a1 : a0;
                float m2 = (kq & 1) ? a3 : a2;
                float s1 = m1 + r1;            // gate (kq&1)     over kq-pair
                float s2 = m2 + r2;            // gate (kq&1)+2   over kq-pair
                float t3 = (kq < 2) ? s2 : s1;
                float r3 = __shfl_xor(t3, 32, 64);
                float mine = (kq < 2) ? s1 : s2;
                float z = mine + r3 + zcur;    // + x@W1 + b1 (precomputed, own gate)

                // branchless activation of gate kq (tanh for gate 2 via 2*sigm(2z)-1)
                float zin = (kq == 2) ? 2.f * z : z;
                float sg  = 1.f / (1.f + __expf(-zin));
                float a   = (kq == 2) ? 2.f * sg - 1.f : sg;
                // all-gather the 4 activated gates
                float g16 = __shfl_xor(a, 16, 64);
                float g32 = __shfl_xor(a, 32, 64);
                float g48 = __shfl_xor(g16, 32, 64);
                float gi = (kq==0) ? a   : (kq==1) ? g16 : (kq==2) ? g32 : g48;
                float gf = (kq==0) ? g16 : (kq==1) ? a   : (kq==2) ? g48 : g32;
                float gc = (kq==0) ? g32 : (kq==1) ? g48 : (kq==2) ? a   : g16;
                float go = (kq==0) ? g48 : (kq==1) ? g32 : (kq==2) ? g16 : a;
                c1 = gf * c1 + gi * gc;
                float h = go * tanh_f(c1);
                if (kq == 0) h1b[p ^ 1][u] = h;
                zcur = znx;
            }
            if (tid == 0 && n >= 2) {
                float s = pbuf[p][0] + pbuf[p][1] + pbuf[p][2] + pbuf[p][3];
                out[(size_t)b * TT + (n - 2)] = sigmf(s + bd0);
            }
            __syncthreads();
        }
    } else {
        // ---------- layer-2 engine: computes h2(n-1) at iter n ----------
        const int w2i = wid - 4;
        const int u = w2i * 16 + ul;
        // K = [h1(64) | h2(64)], my chunk = 32 rows: kq0/1 -> W2 halves, kq2/3 -> U2 halves
        float ww[4][32];
        const float* WU = (kq < 2) ? W2 : U2;
        const int r0 = (kq & 1) * 32;
        #pragma unroll
        for (int g = 0; g < 4; ++g)
            #pragma unroll
            for (int j = 0; j < 32; ++j)
                ww[g][j] = WU[(r0 + j) * GG + (g * HH + u)];
        const float b2v = b2[kq * HH + u];     // bias of MY gate (added post-combine)
        const float wdu = Wd[u];
        float c2 = 0.f;

        for (int n = 0; n < TT + 2; ++n) {
            const int p = n & 1;
            if (n >= 1 && n <= TT) {
                float a0 = 0.f, a1 = 0.f, a2 = 0.f, a3 = 0.f;
                const float* hbase = (kq < 2) ? &h1b[p][(kq & 1) * 32]
                                              : &h2b[p][(kq & 1) * 32];
                const float4* hp = (const float4*)hbase;
                #pragma unroll
                for (int j4 = 0; j4 < 8; ++j4) {
                    float4 hv = hp[j4];
                    a0 += hv.x * ww[0][4*j4+0]; a0 += hv.y * ww[0][4*j4+1];
                    a0 += hv.z * ww[0][4*j4+2]; a0 += hv.w * ww[0][4*j4+3];
                    a1 += hv.x * ww[1][4*j4+0]; a1 += hv.y * ww[1][4*j4+1];
                    a1 += hv.z * ww[1][4*j4+2]; a1 += hv.w * ww[1][4*j4+3];
                    a2 += hv.x * ww[2][4*j4+0]; a2 += hv.y * ww[2][4*j4+1];
                    a2 += hv.z * ww[2][4*j4+2]; a2 += hv.w * ww[2][4*j4+3];
                    a3 += hv.x * ww[3][4*j4+0]; a3 += hv.y * ww[3][4*j4+1];
                    a3 += hv.z * ww[3][4*j4+2]; a3 += hv.w * ww[3][4*j4+3];
                }
                float t1 = (kq & 1) ? a0 : a1;
                float t2 = (kq & 1) ? a2 : a3;
                float r1 = __shfl_xor(t1, 16, 64);
                float r2 = __shfl_xor(t2, 16, 64);
                float m1 = (kq & 1) ? a1 : a0;
                float m2 = (kq & 1) ? a3 : a2;
                float s1 = m1 + r1;
                float s2 = m2 + r2;
                float t3 = (kq < 2) ? s2 : s1;
                float r3 = __shfl_xor(t3, 32, 64);
                float mine = (kq < 2) ? s1 : s2;
                float z = mine + r3 + b2v;

                float zin = (kq == 2) ? 2.f * z : z;
                float sg  = 1.f / (1.f + __expf(-zin));
                float a   = (kq == 2) ? 2.f * sg - 1.f : sg;
                float g16 = __shfl_xor(a, 16, 64);
                float g32 = __shfl_xor(a, 32, 64);
                float g48 = __shfl_xor(g16, 32, 64);
                float gi = (kq==0) ? a   : (kq==1) ? g16 : (kq==2) ? g32 : g48;
                float gf = (kq==0) ? g16 : (kq==1) ? a   : (kq==2) ? g48 : g32;
                float gc = (kq==0) ? g32 : (kq==1) ? g48 : (kq==2) ? a   : g16;
                float go = (kq==0) ? g48 : (kq==1) ? g32 : (kq==2) ? g16 : a;
                c2 = gf * c2 + gi * gc;
                float h = go * tanh_f(c2);
                if (kq == 0) h2b[p ^ 1][u] = h;
                // output projection partial over this wave's 16 units
                float v = (kq == 0) ? h * wdu : 0.f;
                v += __shfl_xor(v, 1, 64);
                v += __shfl_xor(v, 2, 64);
                v += __shfl_xor(v, 4, 64);
                v += __shfl_xor(v, 8, 64);
                if (l == 0) pbuf[p ^ 1][w2i] = v;
            }
            __syncthreads();
        }
    }
}

// ---------------- fallback (R2 structure) if workspace too small for zx ----------------
__global__ __launch_bounds__(512, 2)
void dlstm_fallback(const float* __restrict__ x,
                    const float* __restrict__ W1, const float* __restrict__ U1,
                    const float* __restrict__ b1,
                    const float* __restrict__ W2, const float* __restrict__ U2,
                    const float* __restrict__ b2,
                    const float* __restrict__ Wd, const float* __restrict__ bd,
                    float* __restrict__ out)
{
    const int tid = threadIdx.x;
    const int b   = blockIdx.x;
    const int wid = tid >> 6;
    const int l   = tid & 63;
    const int g   = l >> 4;
    const int uo  = l & 15;

    __shared__ __align__(16) float h1b[2][HH];
    __shared__ __align__(16) float h2b[2][HH];
    __shared__ float pbuf[2][4];

    if (tid < HH) { h1b[0][tid] = 0.f; h1b[1][tid] = 0.f; h2b[0][tid] = 0.f; h2b[1][tid] = 0.f; }
    if (tid < 8) pbuf[tid >> 2][tid & 3] = 0.f;
    __syncthreads();

    if (wid < 4) {
        const int u   = (wid << 4) + uo;
        const int col = (g << 6) + u;
        float w1c[DD], u1c[HH];
        #pragma unroll
        for (int d = 0; d < DD; ++d) w1c[d] = W1[d * GG + col];
        #pragma unroll
        for (int j = 0; j < HH; ++j) u1c[j] = U1[j * GG + col];
        const float b1k = b1[col], bd0 = bd[0];
        float c1 = 0.f;
        const float* xrow = x + (size_t)b * (TT * DD);
        float4 xv[8];
        #pragma unroll
        for (int q = 0; q < 8; ++q) xv[q] = ((const float4*)xrow)[q];

        for (int n = 0; n < TT + 2; ++n) {
            const int p = n & 1;
            if (n < TT) {
                const float4* xnp = (const float4*)(xrow + (size_t)((n + 1 < TT) ? n + 1 : n) * DD);
                float4 xn[8];
                #pragma unroll
                for (int q = 0; q < 8; ++q) xn[q] = xnp[q];
                float a0 = b1k, a1 = 0.f, a2 = 0.f, a3 = 0.f;
                #pragma unroll
                for (int q = 0; q < 8; ++q) {
                    a0 += xv[q].x * w1c[4*q+0]; a1 += xv[q].y * w1c[4*q+1];
                    a2 += xv[q].z * w1c[4*q+2]; a3 += xv[q].w * w1c[4*q+3];
                }
                const float4* hp = (const float4*)h1b[p];
                #pragma unroll
                for (int q = 0; q < 16; ++q) {
                    float4 hv = hp[q];
                    a0 += hv.x * u1c[4*q+0]; a1 += hv.y * u1c[4*q+1];
                    a2 += hv.z * u1c[4*q+2]; a3 += hv.w * u1c[4*q+3];
                }
                float z = (a0 + a1) + (a2 + a3);
                float a = (g == 2) ? tanh_f(z) : sigmf(z);
                float p16 = __shfl_xor(a, 16, 64);
                float p32 = __shfl_xor(a, 32, 64);
                float p48 = __shfl_xor(p16, 32, 64);
                float gi = (g==0) ? a   : (g==1) ? p16 : (g==2) ? p32 : p48;
                float gf = (g==0) ? p16 : (g==1) ? a   : (g==2) ? p48 : p32;
                float gc = (g==0) ? p32 : (g==1) ? p48 : (g==2) ? a   : p16;
                float go = (g==0) ? p48 : (g==1) ? p32 : (g==2) ? p16 : a;
                c1 = gf * c1 + gi * gc;
                float h = go * tanh_f(c1);
                if (g == 0) h1b[p ^ 1][u] = h;
                #pragma unroll
                for (int q = 0; q < 8; ++q) xv[q] = xn[q];
            }
            if (tid == 0 && n >= 2) {
                float s = pbuf[p][0] + pbuf[p][1] + pbuf[p][2] + pbuf[p][3];
                out[(size_t)b * TT + (n - 2)] = sigmf(s + bd0);
            }
            __syncthreads();
        }
    } else {
        const int w2i = wid - 4;
        const int u   = (w2i << 4) + uo;
        const int col = (g << 6) + u;
        float w2c[HH], u2c[HH];
        #pragma unroll
        for (int j = 0; j < HH; ++j) w2c[j] = W2[j * GG + col];
        #pragma unroll
        for (int j = 0; j < HH; ++j) u2c[j] = U2[j * GG + col];
        const float b2k = b2[col];
        const float wdk = Wd[u];
        float c2 = 0.f;

        for (int n = 0; n < TT + 2; ++n) {
            const int p = n & 1;
            if (n >= 1 && n <= TT) {
                float d0 = b2k, d1 = 0.f, d2 = 0.f, d3 = 0.f;
                const float4* h1p = (const float4*)h1b[p];
                const float4* h2p = (const float4*)h2b[p];
                #pragma unroll
                for (int q = 0; q < 16; ++q) {
                    float4 hv = h1p[q];
                    d0 += hv.x * w2c[4*q+0]; d1 += hv.y * w2c[4*q+1];
                    d2 += hv.z * w2c[4*q+2]; d3 += hv.w * w2c[4*q+3];
                }
                #pragma unroll
                for (int q = 0; q < 16; ++q) {
                    float4 hv = h2p[q];
                    d0 += hv.x * u2c[4*q+0]; d1 += hv.y * u2c[4*q+1];
                    d2 += hv.z * u2c[4*q+2]; d3 += hv.w * u2c[4*q+3];
                }
                float z = (d0 + d1) + (d2 + d3);
                float a = (g == 2) ? tanh_f(z) : sigmf(z);
                float p16 = __shfl_xor(a, 16, 64);
                float p32 = __shfl_xor(a, 32, 64);
                float p48 = __shfl_xor(p16, 32, 64);
                float gi = (g==0) ? a   : (g==1) ? p16 : (g==2) ? p32 : p48;
                float gf = (g==0) ? p16 : (g==1) ? a   : (g==2) ? p48 : p32;
                float gc = (g==0) ? p32 : (g==1) ? p48 : (g==2) ? a   : p16;
                float go = (g==0) ? p48 : (g==1) ? p32 : (g==2) ? p16 : a;
                c2 = gf * c2 + gi * gc;
                float h = go * tanh_f(c2);
                if (g == 0) h2b[p ^ 1][u] = h;
                float v = (g == 0) ? h * wdk : 0.f;
                v += __shfl_xor(v, 1, 64);
                v += __shfl_xor(v, 2, 64);
                v += __shfl_xor(v, 4, 64);
                v += __shfl_xor(v, 8, 64);
                if (l == 0) pbuf[p ^ 1][w2i] = v;
            }
            __syncthreads();
        }
    }
}

extern "C" void kernel_launch(void* const* d_in, const int* in_sizes, int n_in,
                              void* d_out, int out_size, void* d_ws, size_t ws_size,
                              hipStream_t stream) {
    const float* x  = (const float*)d_in[0];
    const float* W1 = (const float*)d_in[1];
    const float* U1 = (const float*)d_in[2];
    const float* b1 = (const float*)d_in[3];
    const float* W2 = (const float*)d_in[4];
    const float* U2 = (const float*)d_in[5];
    const float* b2 = (const float*)d_in[6];
    const float* Wd = (const float*)d_in[7];
    const float* bd = (const float*)d_in[8];
    float* out = (float*)d_out;

    const size_t need_f32  = (size_t)BB * TT * GG * sizeof(float);
    const size_t need_bf16 = (size_t)BB * TT * GG * sizeof(__hip_bfloat16);

    if (ws_size >= need_f32) {
        float* zx = (float*)d_ws;
        zx_pre<float><<<dim3(TT / 8, BB), dim3(256), 0, stream>>>(x, W1, b1, zx);
        dlstm_rec<float><<<dim3(BB), dim3(512), 0, stream>>>(zx, U1, W2, U2, b2, Wd, bd, out);
    } else if (ws_size >= need_bf16) {
        __hip_bfloat16* zx = (__hip_bfloat16*)d_ws;
        zx_pre<__hip_bfloat16><<<dim3(TT / 8, BB), dim3(256), 0, stream>>>(x, W1, b1, zx);
        dlstm_rec<__hip_bfloat16><<<dim3(BB), dim3(512), 0, stream>>>(zx, U1, W2, U2, b2, Wd, bd, out);
    } else {
        dlstm_fallback<<<dim3(BB), dim3(512), 0, stream>>>(x, W1, U1, b1, W2, U2, b2, Wd, bd, out);
    }
}